// Round 7
// baseline (409.298 us; speedup 1.0000x reference)
//
#include <hip/hip_runtime.h>

// LongformerSelfAttention (B=32,S=512,H=1024,NH=16,HD=64)
// Round 7 = round-6 resubmitted verbatim (round-6 bench failed at container
// acquisition with no timing metadata -> infra flake, kernel never ran).
// k_qkv8: 8-phase 256x256 double-buffered MFMA GEMM (T2 chunk-XOR swizzle +
// T3/T4 counted vmcnt + T5 setprio), raw s_barrier choreography:
//   per K-tile pair (buf0=even, buf1=odd), phases p1-p8:
//   p1: read B(all)+A(q0) of even tile; stage A0(odd+0)   -> buf1
//   p2: read A(q1);                     stage A1(odd+0)   -> buf1
//   p3: read A(q2);                     stage B0(even+2)  -> buf0  [B reads done p1]
//   p4: read A(q3);                     stage B1(even+2); vmcnt(4)
//   p5-p8: same on odd tile, staging A(even+2)->buf0, B(odd+2)->buf1; vmcnt(4)
//   Every stage lands >=1 barrier after the last read of the region it overwrites.
// NOTE: reshape(b,NH,s,HD) is a pure VIEW: q[b,n,s,d] = flat[bn*32768 + s*64 + d].
// k_tr implements exactly this view's transpose; do NOT "fix" it to the permute form.

typedef unsigned short ushort_t;
typedef __attribute__((ext_vector_type(8))) short short8;
typedef __attribute__((ext_vector_type(8))) unsigned short ushort8;
typedef __attribute__((ext_vector_type(4))) float f32x4;

#define ASYNC16(gp, lp) __builtin_amdgcn_global_load_lds( \
    (const __attribute__((address_space(1))) void*)(gp),  \
    (__attribute__((address_space(3))) void*)(lp), 16, 0, 0)

__device__ __forceinline__ ushort_t f2b(float f) {
  union { float f; unsigned int u; } v; v.f = f;
  unsigned int r = v.u + 0x7FFFu + ((v.u >> 16) & 1u);
  return (ushort_t)(r >> 16);
}
__device__ __forceinline__ float b2f(ushort_t b) {
  union { unsigned int u; float f; } v; v.u = ((unsigned int)b) << 16;
  return v.f;
}

// ---- workspace layout (bytes), total 142,082,048 ----
#define OFF_HSB 0ull
#define OFF_WQT (33554432ull)
#define OFF_WKT (OFF_WQT + 2097152ull)
#define OFF_WVT (OFF_WKT + 2097152ull)
#define OFF_WPT (OFF_WVT + 2097152ull)
#define OFF_QF  (OFF_WPT + 1572864ull)
#define OFF_KF  (OFF_QF + 33554432ull)
#define OFF_VF  (OFF_KF + 33554432ull)

// ---------------- k_cast ----------------
extern "C" __global__ __launch_bounds__(256) void k_cast(
    const float* __restrict__ src, ushort_t* __restrict__ dst) {
  int i = blockIdx.x * 256 + threadIdx.x;
  const float4* s = (const float4*)src + (size_t)i * 2;
  float4 a = s[0], b = s[1];
  ushort8 o;
  o[0] = f2b(a.x); o[1] = f2b(a.y); o[2] = f2b(a.z); o[3] = f2b(a.w);
  o[4] = f2b(b.x); o[5] = f2b(b.y); o[6] = f2b(b.z); o[7] = f2b(b.w);
  *((ushort8*)dst + i) = o;
}

// ---------------- k_wt ----------------
extern "C" __global__ __launch_bounds__(256) void k_wt(
    const float* __restrict__ s0, const float* __restrict__ s1,
    const float* __restrict__ s2, const float* __restrict__ s3,
    ushort_t* __restrict__ d0, ushort_t* __restrict__ d1,
    ushort_t* __restrict__ d2, ushort_t* __restrict__ d3) {
  int z = blockIdx.z;
  const float* src = (z == 0) ? s0 : (z == 1) ? s1 : (z == 2) ? s2 : s3;
  ushort_t* dst    = (z == 0) ? d0 : (z == 1) ? d1 : (z == 2) ? d2 : d3;
  int R = (z == 3) ? 1536 : 1024;
  int C = (z == 3) ? 512  : 1024;
  int c0 = blockIdx.x * 64, r0 = blockIdx.y * 64;
  if (c0 >= C || r0 >= R) return;
  __shared__ ushort_t tl[64][80];
  int t = threadIdx.x;
  {
    int lr = t >> 2, cg = (t & 3) * 16;
    const float* sp = src + (size_t)(r0 + lr) * C + c0 + cg;
    #pragma unroll
    for (int i = 0; i < 16; ++i) tl[lr][cg + i] = f2b(sp[i]);
  }
  __syncthreads();
  {
    int lc = t >> 2, rg = (t & 3) * 16;
    ushort_t* dp = dst + (size_t)(c0 + lc) * R + r0 + rg;
    #pragma unroll
    for (int i = 0; i < 16; ++i) dp[i] = tl[rg + i][lc];
  }
}

// ---------------- k_qkv8: 8-phase 256^2 double-buffered GEMM ----------------
// C[16384][1024] = hsb @ WT^T + bias (per z). 512 thr = 8 waves (2M x 4N),
// per-wave 128x64 out. LDS 128KB: sA/sB [2 buf][256 rows][64 k], chunk-XOR swz.
#define MF(a, b, c) __builtin_amdgcn_mfma_f32_16x16x32_bf16(a, b, c, 0, 0, 0)
#define FENCE asm volatile("" ::: "memory")
#define BAR { FENCE; __builtin_amdgcn_s_barrier(); FENCE; }
#define VMW(N) { asm volatile("s_waitcnt vmcnt(" #N ")" ::: "memory"); \
                 __builtin_amdgcn_sched_barrier(0); }

extern "C" __global__ __launch_bounds__(512) void k_qkv8(
    const ushort_t* __restrict__ A,
    const ushort_t* __restrict__ WTq, const ushort_t* __restrict__ WTk, const ushort_t* __restrict__ WTv,
    const float* __restrict__ bq, const float* __restrict__ bk, const float* __restrict__ bv,
    ushort_t* __restrict__ Qf, ushort_t* __restrict__ Kf, ushort_t* __restrict__ Vf) {
  int z = blockIdx.z;
  const ushort_t* WT = (z == 0) ? WTq : (z == 1) ? WTk : WTv;
  const float* bias  = (z == 0) ? bq  : (z == 1) ? bk  : bv;
  ushort_t* out      = (z == 0) ? Qf  : (z == 1) ? Kf  : Vf;

  // XCD swizzle: per-z 256 blocks, each XCD gets 32 contiguous nl (8 mt x 4 nt).
  int lin = blockIdx.y * 4 + blockIdx.x;
  int nl = (lin & 7) * 32 + (lin >> 3);
  int m0 = (nl >> 2) * 256, n0 = (nl & 3) * 256;

  __shared__ ushort_t sA[2][256 * 64];
  __shared__ ushort_t sB[2][256 * 64];

  int t = threadIdx.x, lane = t & 63, w = t >> 6;
  int wm = w >> 2, wn = w & 3;
  int rowA = wm * 128 + (lane & 15);
  int rowB = wn * 64 + (lane & 15);
  int ckh = lane >> 4;                 // 16B-chunk sub-index from lane
  int swk = lane & 7;                  // XOR swizzle key (row&7 == lane&7 here)

  // stage one 128-row half: LDS dest linear, global source chunk pre-XOR'd
  #define STG_A(buf, tt, h) { \
    _Pragma("unroll") for (int j = 0; j < 2; ++j) { \
      int u = j * 512 + t; int r = u >> 3, c = (u & 7) ^ (r & 7); \
      ASYNC16(A + (size_t)(m0 + (h) * 128 + r) * 1024 + (tt) * 64 + c * 8, \
              (char*)&sA[buf][0] + (h) * 16384 + (j * 512 + w * 64) * 16); } }
  #define STG_B(buf, tt, h) { \
    _Pragma("unroll") for (int j = 0; j < 2; ++j) { \
      int u = j * 512 + t; int r = u >> 3, c = (u & 7) ^ (r & 7); \
      ASYNC16(WT + (size_t)(n0 + (h) * 128 + r) * 1024 + (tt) * 64 + c * 8, \
              (char*)&sB[buf][0] + (h) * 16384 + (j * 512 + w * 64) * 16); } }

  // swizzled reads: byte = (row*8 + chunk)*16, chunk = (kk*4+ckh) ^ swk
  #define LDA(buf, m, kk) (*(const short8*)((const char*)&sA[buf][0] + \
      (((rowA + (m) * 16) * 8 + (((kk) * 4 + ckh) ^ swk)) << 4)))
  #define LDB(buf, n, kk) (*(const short8*)((const char*)&sB[buf][0] + \
      (((rowB + (n) * 16) * 8 + (((kk) * 4 + ckh) ^ swk)) << 4)))

  #define RDA(buf, q) { a0 = LDA(buf, 2*(q), 0); a1 = LDA(buf, 2*(q), 1); \
                        a2 = LDA(buf, 2*(q)+1, 0); a3 = LDA(buf, 2*(q)+1, 1); }
  #define RDB(buf) { _Pragma("unroll") for (int n = 0; n < 4; ++n) { \
                       bfr[n][0] = LDB(buf, n, 0); bfr[n][1] = LDB(buf, n, 1); } }
  #define DOMM(q) { __builtin_amdgcn_s_setprio(1); \
    _Pragma("unroll") for (int n = 0; n < 4; ++n) { \
      acc[2*(q)][n]   = MF(a0, bfr[n][0], acc[2*(q)][n]); \
      acc[2*(q)][n]   = MF(a1, bfr[n][1], acc[2*(q)][n]); \
      acc[2*(q)+1][n] = MF(a2, bfr[n][0], acc[2*(q)+1][n]); \
      acc[2*(q)+1][n] = MF(a3, bfr[n][1], acc[2*(q)+1][n]); } \
    __builtin_amdgcn_s_setprio(0); }

  f32x4 acc[8][4];
  #pragma unroll
  for (int m = 0; m < 8; ++m)
    #pragma unroll
    for (int n = 0; n < 4; ++n)
      acc[m][n] = (f32x4){0.f, 0.f, 0.f, 0.f};
  short8 bfr[4][2], a0, a1, a2, a3;

  // prologue: tile0 full -> buf0; tile1 B -> buf1; wait tile0 (leave 4 in flight)
  STG_B(0, 0, 0); STG_B(0, 0, 1); STG_A(0, 0, 0); STG_A(0, 0, 1);
  STG_B(1, 1, 0); STG_B(1, 1, 1);
  VMW(4); BAR;

  for (int it = 0; it < 7; ++it) {
    int to = 2 * it + 1, t2 = 2 * it + 2, t3 = 2 * it + 3;
    RDB(0); RDA(0, 0); STG_A(1, to, 0); BAR; DOMM(0); BAR;   // p1
    RDA(0, 1);         STG_A(1, to, 1); BAR; DOMM(1); BAR;   // p2
    RDA(0, 2);         STG_B(0, t2, 0); BAR; DOMM(2); BAR;   // p3
    RDA(0, 3);         STG_B(0, t2, 1); BAR; DOMM(3); VMW(4); BAR; // p4
    RDB(1); RDA(1, 0); STG_A(0, t2, 0); BAR; DOMM(0); BAR;   // p5
    RDA(1, 1);         STG_A(0, t2, 1); BAR; DOMM(1); BAR;   // p6
    RDA(1, 2);         STG_B(1, t3, 0); BAR; DOMM(2); BAR;   // p7
    RDA(1, 3);         STG_B(1, t3, 1); BAR; DOMM(3); VMW(4); BAR; // p8
  }
  // it = 7 peeled (tiles 14,15; no tile-16/17 stages; drain at p4)
  RDB(0); RDA(0, 0); STG_A(1, 15, 0); BAR; DOMM(0); BAR;
  RDA(0, 1);         STG_A(1, 15, 1); BAR; DOMM(1); BAR;
  RDA(0, 2);                          BAR; DOMM(2); BAR;
  RDA(0, 3);                          BAR; DOMM(3); VMW(0); BAR;
  RDB(1); RDA(1, 0);                  BAR; DOMM(0); BAR;
  RDA(1, 1);                          BAR; DOMM(1); BAR;
  RDA(1, 2);                          BAR; DOMM(2); BAR;
  RDA(1, 3);                          BAR; DOMM(3); BAR;

  // epilogue
  #pragma unroll
  for (int n = 0; n < 4; ++n) {
    int gc = n0 + wn * 64 + n * 16 + (lane & 15);
    float bv_ = bias[gc];
    #pragma unroll
    for (int m = 0; m < 8; ++m) {
      int gr = m0 + wm * 128 + m * 16 + ((lane >> 4) << 2);
      #pragma unroll
      for (int r = 0; r < 4; ++r)
        out[(size_t)(gr + r) * 1024 + gc] = f2b(acc[m][n][r] + bv_);
    }
  }
  #undef STG_A
  #undef STG_B
  #undef LDA
  #undef LDB
  #undef RDA
  #undef RDB
  #undef DOMM
}

// ---------------- k_tr: per-(b,n) [512][64] -> [64][512] (view-correct) ----------------
extern "C" __global__ __launch_bounds__(256) void k_tr(
    const ushort_t* __restrict__ src, ushort_t* __restrict__ dst) {
  int bn = blockIdx.x;
  const ushort_t* s = src + (size_t)bn * 32768;
  ushort_t* d = dst + (size_t)bn * 32768;
  __shared__ ushort_t tl[64][80];
  int t = threadIdx.x;
  for (int c = 0; c < 8; ++c) {
    #pragma unroll
    for (int j = 0; j < 2; ++j) {
      int u = j * 256 + t;
      int row = u >> 3, ch = (u & 7) * 8;
      uint4 v = *(const uint4*)&s[(size_t)(c * 64 + row) * 64 + ch];
      const ushort_t* pv = (const ushort_t*)&v;
      #pragma unroll
      for (int i = 0; i < 8; ++i) tl[ch + i][row] = pv[i];
    }
    __syncthreads();
    #pragma unroll
    for (int j = 0; j < 2; ++j) {
      int u = j * 256 + t;
      int dd = u >> 3, ch = (u & 7) * 8;
      *(uint4*)&d[(size_t)dd * 512 + c * 64 + ch] = *(const uint4*)&tl[dd][ch];
    }
    __syncthreads();
  }
}

// ---------------- k_p0: p0[bn][s] = sigmoid((q.k)/8) ----------------
extern "C" __global__ __launch_bounds__(256) void k_p0(
    const ushort_t* __restrict__ QT, const ushort_t* __restrict__ KT,
    float* __restrict__ p0buf) {
  int bn = blockIdx.x;
  int t = threadIdx.x;
  const ushort_t* Qb = QT + (size_t)bn * 32768;
  const ushort_t* Kb = KT + (size_t)bn * 32768;
  #pragma unroll
  for (int sc = 0; sc < 2; ++sc) {
    int s = sc * 256 + t;
    float dot = 0.f;
    #pragma unroll 8
    for (int d = 0; d < 64; ++d)
      dot += b2f(Qb[d * 512 + s]) * b2f(Kb[d * 512 + s]);
    p0buf[bn * 512 + s] = 1.0f / (1.0f + __expf(-dot * 0.125f));
  }
}

// ---------------- k_gv2: C[(bn,d)][s] = A @ WpT^T, fused blend epilogue ----------------
extern "C" __global__ __launch_bounds__(256) void k_gv2(
    const ushort_t* __restrict__ QT, const ushort_t* __restrict__ KT, const ushort_t* __restrict__ VT,
    const ushort_t* __restrict__ WpT, const float* __restrict__ p0buf,
    const float* __restrict__ bp, float* __restrict__ out) {
  int glin = blockIdx.y * 8 + blockIdx.x;
  int nl = (glin & 7) * 128 + (glin >> 3);
  int mt = nl >> 2, nt = nl & 3;
  int m0 = mt * 128, n0 = nt * 128;

  __shared__ ushort_t lA[128 * 32];
  __shared__ ushort_t lB[128 * 32];
  int t = threadIdx.x, lane = t & 63, wave = t >> 6;
  int wr = (wave >> 1) * 64, wc = (wave & 1) * 64;

  f32x4 acc[4][4];
  #pragma unroll
  for (int mi = 0; mi < 4; ++mi)
    #pragma unroll
    for (int ni = 0; ni < 4; ++ni)
      acc[mi][ni] = (f32x4){0.f, 0.f, 0.f, 0.f};

  for (int seg = 0; seg < 3; ++seg) {
    const ushort_t* XT = (seg == 0) ? QT : (seg == 1) ? KT : VT;
    for (int kk = 0; kk < 512; kk += 32) {
      int k0 = seg * 512 + kk;
      #pragma unroll
      for (int j = 0; j < 2; ++j) {
        int u = j * 256 + t;
        int ar = m0 + (u >> 2);
        ASYNC16(XT + ((size_t)(ar >> 6) << 15) + (size_t)(ar & 63) * 512 + kk + (u & 3) * 8,
                (char*)lA + (j * 256 + wave * 64) * 16);
      }
      #pragma unroll
      for (int j = 0; j < 2; ++j) {
        int u = j * 256 + t;
        ASYNC16(WpT + (size_t)(n0 + (u >> 2)) * 1536 + k0 + (u & 3) * 8,
                (char*)lB + (j * 256 + wave * 64) * 16);
      }
      __syncthreads();
      short8 af[4], bf[4];
      #pragma unroll
      for (int mi = 0; mi < 4; ++mi)
        af[mi] = *(const short8*)&lA[(wr + mi * 16 + (lane & 15)) * 32 + (lane >> 4) * 8];
      #pragma unroll
      for (int ni = 0; ni < 4; ++ni)
        bf[ni] = *(const short8*)&lB[(wc + ni * 16 + (lane & 15)) * 32 + (lane >> 4) * 8];
      #pragma unroll
      for (int mi = 0; mi < 4; ++mi)
        #pragma unroll
        for (int ni = 0; ni < 4; ++ni)
          acc[mi][ni] = MF(af[mi], bf[ni], acc[mi][ni]);
      __syncthreads();
    }
  }

  #pragma unroll
  for (int mi = 0; mi < 4; ++mi) {
    int r0 = m0 + wr + mi * 16 + ((lane >> 4) << 2);
    int bn = r0 >> 6, d0 = r0 & 63;
    int b = bn >> 4, nh = bn & 15;
    const ushort_t* VTb = VT + ((size_t)bn << 15);
    const float* p0row = p0buf + bn * 512;
    size_t outb = (size_t)b * 524288 + (size_t)nh * 64 + d0;
    #pragma unroll
    for (int ni = 0; ni < 4; ++ni) {
      int gc = n0 + wc + ni * 16 + (lane & 15);
      float p0 = p0row[gc];
      float bpv = bp[gc];
      float4 o;
      #pragma unroll
      for (int r = 0; r < 4; ++r) {
        float g = acc[mi][ni][r] + bpv;
        float ge = 0.5f * g * (1.0f + erff(g / 1.41421f));
        float v = b2f(VTb[(size_t)(d0 + r) * 512 + gc]);
        ((float*)&o)[r] = p0 * v + (1.0f - p0) * ge;
      }
      *(float4*)&out[outb + (size_t)gc * 1024] = o;
    }
  }
}

extern "C" void kernel_launch(void* const* d_in, const int* in_sizes, int n_in,
                              void* d_out, int out_size, void* d_ws, size_t ws_size,
                              hipStream_t stream) {
  const float* hs = (const float*)d_in[0];
  const float* Wq = (const float*)d_in[1];
  const float* bq = (const float*)d_in[2];
  const float* Wk = (const float*)d_in[3];
  const float* bk = (const float*)d_in[4];
  const float* Wv = (const float*)d_in[5];
  const float* bv = (const float*)d_in[6];
  const float* Wp = (const float*)d_in[7];
  const float* bp = (const float*)d_in[8];

  char* w = (char*)d_ws;
  ushort_t* hsb = (ushort_t*)(w + OFF_HSB);
  ushort_t* WqT = (ushort_t*)(w + OFF_WQT);
  ushort_t* WkT = (ushort_t*)(w + OFF_WKT);
  ushort_t* WvT = (ushort_t*)(w + OFF_WVT);
  ushort_t* WpT = (ushort_t*)(w + OFF_WPT);
  ushort_t* Qf  = (ushort_t*)(w + OFF_QF);
  ushort_t* Kf  = (ushort_t*)(w + OFF_KF);
  ushort_t* Vf  = (ushort_t*)(w + OFF_VF);
  // aliases over dead buffers (sequential launches keep this safe):
  ushort_t* QTt = (ushort_t*)(w + OFF_HSB);  // QT overwrites hsb (dead after k_qkv8)
  ushort_t* KTt = (ushort_t*)(w + OFF_QF);   // KT overwrites Qf  (dead after k_tr #1)
  ushort_t* VTt = (ushort_t*)(w + OFF_KF);   // VT overwrites Kf  (dead after k_tr #2)
  float*    p0b = (float*)(w + OFF_VF);      // p0 overwrites Vf  (dead after k_tr #3)

  k_cast<<<8192, 256, 0, stream>>>(hs, hsb);
  k_wt<<<dim3(16, 24, 4), 256, 0, stream>>>(Wq, Wk, Wv, Wp, WqT, WkT, WvT, WpT);
  k_qkv8<<<dim3(4, 64, 3), 512, 0, stream>>>(hsb, WqT, WkT, WvT, bq, bk, bv, Qf, Kf, Vf);
  k_tr<<<512, 256, 0, stream>>>(Qf, QTt);
  k_tr<<<512, 256, 0, stream>>>(Kf, KTt);
  k_tr<<<512, 256, 0, stream>>>(Vf, VTt);
  k_p0<<<512, 256, 0, stream>>>(QTt, KTt, p0b);
  k_gv2<<<dim3(8, 128), 256, 0, stream>>>(QTt, KTt, VTt, WpT, p0b, bp, (float*)d_out);
}